// Round 9
// baseline (1110.964 us; speedup 1.0000x reference)
//
#include <hip/hip_runtime.h>
#include <hip/hip_bf16.h>
#include <math.h>

#define B_   8
#define NSEQ 1024
#define T_   (B_*NSEQ)     // 8192 tokens
#define DIN  64
#define D_   512
#define H_   8
#define HD_  64
#define FF_  2048
#define L_   6
#define C_   5

typedef __attribute__((ext_vector_type(8))) short bf16x8;
typedef __attribute__((ext_vector_type(4))) float f32x4;

__device__ __forceinline__ unsigned short f2bf(float f) {
    __hip_bfloat16 h = __float2bfloat16(f);
    return *reinterpret_cast<unsigned short*>(&h);
}
__device__ __forceinline__ float bf2f(unsigned short u) {
    __hip_bfloat16 h = *reinterpret_cast<__hip_bfloat16*>(&u);
    return __bfloat162float(h);
}

__device__ __forceinline__ void gload_lds16(const void* g, void* l) {
    __builtin_amdgcn_global_load_lds(
        (const __attribute__((address_space(1))) unsigned int*)g,
        (__attribute__((address_space(3))) unsigned int*)l, 16, 0, 0);
}

// ---------------------------------------------------------------------------
// bf16 MFMA GEMM, 2-phase double-buffered + bijective XCD swizzle (T1).
// BM=128, BK=64, BN template (128 or 64). 4 waves (2x2), 16x16x32 MFMA,
// XOR-swizzled LDS, global_load_lds staging overlapped with compute.
// OMODE: 0 = f32 out, 1 = bf16 out, 2 = both (Cout=f32, Cout2=bf16).
// Grid must have (gx*gy) % 8 == 0 (all our grids: 768/512/1024).
// ---------------------------------------------------------------------------
template<bool RELU, int OMODE, int BN>
__global__ __launch_bounds__(256, BN==64 ? 3 : 2)
void gemm_mfma_kernel(const unsigned short* __restrict__ A,
                      const unsigned short* __restrict__ W,
                      const float* __restrict__ bias,
                      void* __restrict__ Cout,
                      unsigned short* __restrict__ Cout2,
                      int M, int N, int K)
{
    constexpr int BM = 128, BK = 64;
    constexpr int NFN = BN/32;            // 4 (BN=128) or 2 (BN=64)
    __shared__ short As[2][BM*BK];
    __shared__ short Bs[2][BN*BK];
    const int tid = threadIdx.x;
    const int l   = tid & 63;
    const int wid = tid >> 6;
    const int wm  = wid >> 1, wn = wid & 1;

    // XCD swizzle: contiguous chunk of tiles per XCD for A-panel L2 reuse.
    const int gx  = gridDim.x;
    const int nwg = gx * gridDim.y;
    int bid = blockIdx.y * gx + blockIdx.x;
    bid = (bid & 7) * (nwg >> 3) + (bid >> 3);
    const int bm = (bid / gx) * BM;
    const int bn = (bid % gx) * BN;

    const int srow = l >> 3;
    const int scol = ((l & 7) ^ srow) * 8;

    f32x4 acc[4][NFN];
    const f32x4 z = {0.f, 0.f, 0.f, 0.f};
    #pragma unroll
    for (int m = 0; m < 4; m++)
        #pragma unroll
        for (int n = 0; n < NFN; n++) acc[m][n] = z;

    const int nk = K / BK;

    auto stage = [&](int kt, int sb) {
        const int k0 = kt * BK;
        #pragma unroll
        for (int c = 0; c < 4; c++) {
            const int r = wid*32 + c*8 + srow;
            gload_lds16(A + (size_t)(bm + r)*K + k0 + scol, &As[sb][(wid*32 + c*8)*64]);
        }
        #pragma unroll
        for (int c = 0; c < BN/32; c++) {
            const int r = wid*(BN/4) + c*8 + srow;
            gload_lds16(W + (size_t)(bn + r)*K + k0 + scol, &Bs[sb][(wid*(BN/4) + c*8)*64]);
        }
    };

    stage(0, 0);
    int buf = 0;
    for (int kt = 0; kt < nk; kt++) {
        __syncthreads();   // drains stage(kt) (compiler vmcnt0)
        if (kt + 1 < nk) stage(kt + 1, buf ^ 1);   // in flight under compute(kt)

        #pragma unroll
        for (int h = 0; h < 2; h++) {
            bf16x8 af[4], bfr[NFN];
            #pragma unroll
            for (int m = 0; m < 4; m++) {
                const int R  = wm*64 + m*16 + (l & 15);
                const int cb = (h*64 + (l >> 4)*16) ^ ((R & 7) << 4);
                af[m] = *(const bf16x8*)((const char*)&As[buf][0] + R*128 + cb);
            }
            #pragma unroll
            for (int n = 0; n < NFN; n++) {
                const int Rc = wn*(BN/2) + n*16 + (l & 15);
                const int cb = (h*64 + (l >> 4)*16) ^ ((Rc & 7) << 4);
                bfr[n] = *(const bf16x8*)((const char*)&Bs[buf][0] + Rc*128 + cb);
            }
            #pragma unroll
            for (int m = 0; m < 4; m++)
                #pragma unroll
                for (int n = 0; n < NFN; n++)
                    acc[m][n] = __builtin_amdgcn_mfma_f32_16x16x32_bf16(af[m], bfr[n], acc[m][n], 0, 0, 0);
        }
        buf ^= 1;
    }

    // C/D layout: col = lane&15, row = (lane>>4)*4 + reg   [m89-verified]
    #pragma unroll
    for (int n = 0; n < NFN; n++) {
        const int col = bn + wn*(BN/2) + n*16 + (l & 15);
        const float bv = bias[col];
        #pragma unroll
        for (int m = 0; m < 4; m++) {
            const int row0 = bm + wm*64 + m*16 + ((l >> 4) << 2);
            #pragma unroll
            for (int j = 0; j < 4; j++) {
                float t = acc[m][n][j] + bv;
                if (RELU) t = fmaxf(t, 0.f);
                const size_t idx = (size_t)(row0 + j)*N + col;
                if (OMODE == 1)
                    ((unsigned short*)Cout)[idx] = f2bf(t);
                else
                    ((float*)Cout)[idx] = t;
                if (OMODE == 2)
                    Cout2[idx] = f2bf(t);
            }
        }
    }
}

// ---------------------------------------------------------------------------
// bf16 MFMA flash attention v5: 4 waves x 32 q-rows = 128 q-rows/block.
// KV tile 64, K dbuf via global_load_lds (XOR-swizzle), V dbuf reg-staged,
// swapped QK^T, in-lane softmax with defer-max (THR=8 scaled / 64 raw),
// exp2-folded scale, unrounded p-sum, setprio around MFMA clusters.
// ---------------------------------------------------------------------------
__global__ __launch_bounds__(256, 2)
void attn_mfma_kernel(const unsigned short* __restrict__ QKV,
                      const unsigned char* __restrict__ mask,
                      unsigned short* __restrict__ O)
{
    constexpr int QS = 1536;
    constexpr float CEXP = 0.18033688f;   // 0.125 * log2(e)
    __shared__ short Ks[2][64*64];   // K tiles, linear 128B rows, XOR-swizzled
    __shared__ short Vt[2][64*72];   // V transposed [d][kv], pitch 72
    __shared__ short Ps[4][32*72];   // per-wave P [32 q][kv], pitch 72
    const int tid = threadIdx.x;
    const int l   = tid & 63;
    const int w   = tid >> 6;
    const int g   = l >> 4;          // lane group 0..3
    const int q16 = l & 15;
    const int b   = blockIdx.y >> 3;
    const int h   = blockIdx.y & 7;
    const int q0  = blockIdx.x * 128;
    const int qb  = q0 + w*32;       // wave's 32 q-rows
    const size_t tokbase = (size_t)b * NSEQ;

    // Q fragments (B-operand): frag qf covers q-rows qb+qf*16+q16
    bf16x8 bq[2][2];
    #pragma unroll
    for (int qf = 0; qf < 2; qf++) {
        const unsigned short* qp = QKV + (tokbase + qb + qf*16 + q16)*QS + h*HD_ + g*8;
        bq[qf][0] = *(const bf16x8*)qp;
        bq[qf][1] = *(const bf16x8*)(qp + 32);
    }

    f32x4 accO[2][4];
    const f32x4 z = {0.f,0.f,0.f,0.f};
    #pragma unroll
    for (int qf = 0; qf < 2; qf++)
        #pragma unroll
        for (int n = 0; n < 4; n++) accO[qf][n] = z;
    float mrow[2] = {-INFINITY, -INFINITY};   // RAW-score domain
    float lrow[2] = {0.f, 0.f};

    const int srow = l >> 3;
    const int scol = ((l & 7) ^ srow) * 8;
    const unsigned char* mp = mask + (size_t)b*NSEQ;

    // prologue: stage K(0); load+store V(0)
    #pragma unroll
    for (int c = 0; c < 2; c++) {
        const int rb = (w*2 + c)*8;
        gload_lds16(QKV + (tokbase + rb + srow)*QS + D_ + h*HD_ + scol, &Ks[0][rb*64]);
    }
    {
        const unsigned short* vp = QKV + (tokbase + l)*QS + 2*D_ + h*HD_ + w*16;
        const bf16x8 v8a = *(const bf16x8*)vp;
        const bf16x8 v8b = *(const bf16x8*)(vp + 8);
        #pragma unroll
        for (int j = 0; j < 8; j++) {
            Vt[0][(w*16 + j)*72 + l]     = v8a[j];
            Vt[0][(w*16 + 8 + j)*72 + l] = v8b[j];
        }
    }

    for (int t = 0; t < NSEQ/64; t++) {
        const int buf = t & 1;
        const int kv0 = t*64;
        __syncthreads();   // stage(t)+V-writes(t) visible; prev reads of buf^1 done

        // issue stage(t+1): K -> Ks[buf^1], V -> regs (write late)
        bf16x8 nva, nvb;
        const bool more = (t + 1 < NSEQ/64);
        if (more) {
            const int kvn = kv0 + 64;
            #pragma unroll
            for (int c = 0; c < 2; c++) {
                const int rb = (w*2 + c)*8;
                gload_lds16(QKV + (tokbase + kvn + rb + srow)*QS + D_ + h*HD_ + scol,
                            &Ks[buf^1][rb*64]);
            }
            const unsigned short* vp = QKV + (tokbase + kvn + l)*QS + 2*D_ + h*HD_ + w*16;
            nva = *(const bf16x8*)vp;
            nvb = *(const bf16x8*)(vp + 8);
        }

        // QK^T swapped: s4[qf][n][r] = S_raw[kv=16n+4g+r][q = qb+qf*16+q16]
        f32x4 s4[2][4];
        #pragma unroll
        for (int qf = 0; qf < 2; qf++)
            #pragma unroll
            for (int n = 0; n < 4; n++) s4[qf][n] = z;
        __builtin_amdgcn_s_setprio(1);
        #pragma unroll
        for (int ks = 0; ks < 2; ks++) {
            const int cb = (ks*64 + g*16) ^ ((q16 & 7) << 4);
            bf16x8 ak[4];
            #pragma unroll
            for (int n = 0; n < 4; n++)
                ak[n] = *(const bf16x8*)((const char*)&Ks[buf][0] + (n*16 + q16)*128 + cb);
            #pragma unroll
            for (int qf = 0; qf < 2; qf++)
                #pragma unroll
                for (int n = 0; n < 4; n++)
                    s4[qf][n] = __builtin_amdgcn_mfma_f32_16x16x32_bf16(ak[n], bq[qf][ks], s4[qf][n], 0, 0, 0);
        }
        __builtin_amdgcn_s_setprio(0);

        const unsigned long long mbits = __ballot(mp[kv0 + l] != 0);

        // softmax per q-frag: raw-domain max, exp2-folded scale, defer-max
        #pragma unroll
        for (int qf = 0; qf < 2; qf++) {
            float sv[4][4];
            #pragma unroll
            for (int n = 0; n < 4; n++)
                #pragma unroll
                for (int r = 0; r < 4; r++) sv[n][r] = s4[qf][n][r];
            if (mbits) {   // wave-uniform; skipped for all-false mask
                #pragma unroll
                for (int n = 0; n < 4; n++)
                    #pragma unroll
                    for (int r = 0; r < 4; r++)
                        if ((mbits >> (unsigned)(16*n + 4*g + r)) & 1ULL) sv[n][r] = -INFINITY;
            }
            float tmax = sv[0][0];
            #pragma unroll
            for (int n = 0; n < 4; n++)
                #pragma unroll
                for (int r = 0; r < 4; r++) tmax = fmaxf(tmax, sv[n][r]);
            tmax = fmaxf(tmax, __shfl_xor(tmax, 16));
            tmax = fmaxf(tmax, __shfl_xor(tmax, 32));

            unsigned int pw[4][2];
            float rs = 0.f;
            if (__all(tmax <= mrow[qf] + 64.f)) {
                // deferred: keep old max, p bounded by e^8; no rescale
                const float mc = mrow[qf]*CEXP;
                #pragma unroll
                for (int n = 0; n < 4; n++) {
                    const float p0 = exp2f(fmaf(sv[n][0], CEXP, -mc));
                    const float p1 = exp2f(fmaf(sv[n][1], CEXP, -mc));
                    const float p2 = exp2f(fmaf(sv[n][2], CEXP, -mc));
                    const float p3 = exp2f(fmaf(sv[n][3], CEXP, -mc));
                    pw[n][0] = (unsigned)f2bf(p0) | ((unsigned)f2bf(p1) << 16);
                    pw[n][1] = (unsigned)f2bf(p2) | ((unsigned)f2bf(p3) << 16);
                    rs += (p0 + p1) + (p2 + p3);
                }
                rs += __shfl_xor(rs, 16);
                rs += __shfl_xor(rs, 32);
                lrow[qf] += rs;
            } else {
                const float mnew = fmaxf(mrow[qf], tmax);
                const float mc   = mnew*CEXP;
                #pragma unroll
                for (int n = 0; n < 4; n++) {
                    const float p0 = exp2f(fmaf(sv[n][0], CEXP, -mc));
                    const float p1 = exp2f(fmaf(sv[n][1], CEXP, -mc));
                    const float p2 = exp2f(fmaf(sv[n][2], CEXP, -mc));
                    const float p3 = exp2f(fmaf(sv[n][3], CEXP, -mc));
                    pw[n][0] = (unsigned)f2bf(p0) | ((unsigned)f2bf(p1) << 16);
                    pw[n][1] = (unsigned)f2bf(p2) | ((unsigned)f2bf(p3) << 16);
                    rs += (p0 + p1) + (p2 + p3);
                }
                rs += __shfl_xor(rs, 16);
                rs += __shfl_xor(rs, 32);
                const float alpha = exp2f((mrow[qf] - mnew)*CEXP);
                lrow[qf] = lrow[qf]*alpha + rs;
                mrow[qf] = mnew;
                float alr[4];
                #pragma unroll
                for (int r = 0; r < 4; r++) alr[r] = __shfl(alpha, g*4 + r, 16);
                #pragma unroll
                for (int n = 0; n < 4; n++)
                    #pragma unroll
                    for (int r = 0; r < 4; r++) accO[qf][n][r] *= alr[r];
            }

            // P -> LDS row qf*16+q16, kv slots 16n+4g..+3
            #pragma unroll
            for (int n = 0; n < 4; n++) {
                uint2 u; u.x = pw[n][0]; u.y = pw[n][1];
                *(uint2*)&Ps[w][(qf*16 + q16)*72 + 16*n + 4*g] = u;
            }
        }

        // PV: accO[qf][n][r] for q'=qf*16+4g+r, d=16n+q16
        __builtin_amdgcn_s_setprio(1);
        #pragma unroll
        for (int ks = 0; ks < 2; ks++) {
            const bf16x8 ap0 = *(const bf16x8*)&Ps[w][(q16)*72      + ks*32 + g*8];
            const bf16x8 ap1 = *(const bf16x8*)&Ps[w][(16 + q16)*72 + ks*32 + g*8];
            #pragma unroll
            for (int n = 0; n < 4; n++) {
                const bf16x8 bv = *(const bf16x8*)&Vt[buf][(n*16 + q16)*72 + ks*32 + g*8];
                accO[0][n] = __builtin_amdgcn_mfma_f32_16x16x32_bf16(ap0, bv, accO[0][n], 0, 0, 0);
                accO[1][n] = __builtin_amdgcn_mfma_f32_16x16x32_bf16(ap1, bv, accO[1][n], 0, 0, 0);
            }
        }
        __builtin_amdgcn_s_setprio(0);

        // write V(t+1) into Vt[buf^1]
        if (more) {
            #pragma unroll
            for (int j = 0; j < 8; j++) {
                Vt[buf^1][(w*16 + j)*72 + l]     = nva[j];
                Vt[buf^1][(w*16 + 8 + j)*72 + l] = nvb[j];
            }
        }
    }

    // epilogue
    #pragma unroll
    for (int qf = 0; qf < 2; qf++) {
        float linv[4];
        #pragma unroll
        for (int r = 0; r < 4; r++) linv[r] = 1.0f / __shfl(lrow[qf], g*4 + r, 16);
        #pragma unroll
        for (int r = 0; r < 4; r++) {
            unsigned short* op = O + (tokbase + qb + qf*16 + 4*g + r)*D_ + h*HD_;
            #pragma unroll
            for (int n = 0; n < 4; n++)
                op[16*n + q16] = f2bf(accO[qf][n][r] * linv[r]);
        }
    }
}

// ---------------------------------------------------------------------------
// Fused (x += delta_bf16); LayerNorm; bf16 copy out.
// ---------------------------------------------------------------------------
__global__ __launch_bounds__(128)
void add_ln_kernel(float* __restrict__ x, const unsigned short* __restrict__ delta,
                   const float* __restrict__ g, const float* __restrict__ bta,
                   unsigned short* __restrict__ xb_out)
{
    const int row = blockIdx.x;
    const int tid = threadIdx.x;
    float* xr = x + (size_t)row*D_;
    float4 xv = *(const float4*)(xr + tid*4);
    {
        const ushort4 dv = *(const ushort4*)(delta + (size_t)row*D_ + tid*4);
        xv.x += bf2f(dv.x); xv.y += bf2f(dv.y); xv.z += bf2f(dv.z); xv.w += bf2f(dv.w);
    }
    float sum = xv.x + xv.y + xv.z + xv.w;
    float sq  = xv.x*xv.x + xv.y*xv.y + xv.z*xv.z + xv.w*xv.w;
    #pragma unroll
    for (int off = 1; off < 64; off <<= 1) {
        sum += __shfl_xor(sum, off, 64);
        sq  += __shfl_xor(sq,  off, 64);
    }
    __shared__ float red[2][2];
    if ((tid & 63) == 0) { red[tid >> 6][0] = sum; red[tid >> 6][1] = sq; }
    __syncthreads();
    sum = red[0][0] + red[1][0];
    sq  = red[0][1] + red[1][1];
    const float mu  = sum * (1.f/D_);
    const float var = sq * (1.f/D_) - mu*mu;
    const float rs  = rsqrtf(var + 1e-5f);
    const float4 gv = *(const float4*)(g   + tid*4);
    const float4 bv = *(const float4*)(bta + tid*4);
    float4 o;
    o.x = (xv.x - mu)*rs*gv.x + bv.x;
    o.y = (xv.y - mu)*rs*gv.y + bv.y;
    o.z = (xv.z - mu)*rs*gv.z + bv.z;
    o.w = (xv.w - mu)*rs*gv.w + bv.w;
    *(float4*)(xr + tid*4) = o;
    ushort4 u;
    u.x = f2bf(o.x); u.y = f2bf(o.y); u.z = f2bf(o.z); u.w = f2bf(o.w);
    *(ushort4*)(xb_out + (size_t)row*D_ + tid*4) = u;
}

// ---------------------------------------------------------------------------
// Fused final LayerNorm + head: logits[row] = LN(x[row]) @ head_W^T + head_b
// ---------------------------------------------------------------------------
__global__ __launch_bounds__(128)
void ln_head_kernel(const float* __restrict__ x,
                    const float* __restrict__ g, const float* __restrict__ bta,
                    const float* __restrict__ hw, const float* __restrict__ hb,
                    float* __restrict__ out)
{
    const int row = blockIdx.x;
    const int tid = threadIdx.x;
    const float4 xv = *(const float4*)(x + (size_t)row*D_ + tid*4);
    float sum = xv.x + xv.y + xv.z + xv.w;
    float sq  = xv.x*xv.x + xv.y*xv.y + xv.z*xv.z + xv.w*xv.w;
    #pragma unroll
    for (int off = 1; off < 64; off <<= 1) {
        sum += __shfl_xor(sum, off, 64);
        sq  += __shfl_xor(sq,  off, 64);
    }
    __shared__ float red[2][2];
    if ((tid & 63) == 0) { red[tid >> 6][0] = sum; red[tid >> 6][1] = sq; }
    __syncthreads();
    sum = red[0][0] + red[1][0];
    sq  = red[0][1] + red[1][1];
    const float mu  = sum * (1.f/D_);
    const float var = sq * (1.f/D_) - mu*mu;
    const float rs  = rsqrtf(var + 1e-5f);
    const float4 gv = *(const float4*)(g   + tid*4);
    const float4 bv = *(const float4*)(bta + tid*4);
    float o[4];
    o[0] = (xv.x - mu)*rs*gv.x + bv.x;
    o[1] = (xv.y - mu)*rs*gv.y + bv.y;
    o[2] = (xv.z - mu)*rs*gv.z + bv.z;
    o[3] = (xv.w - mu)*rs*gv.w + bv.w;

    float part[C_];
    #pragma unroll
    for (int c = 0; c < C_; c++) {
        const float4 wv = *(const float4*)(hw + c*D_ + tid*4);
        part[c] = o[0]*wv.x + o[1]*wv.y + o[2]*wv.z + o[3]*wv.w;
    }
    #pragma unroll
    for (int c = 0; c < C_; c++)
        #pragma unroll
        for (int off = 1; off < 64; off <<= 1)
            part[c] += __shfl_xor(part[c], off, 64);
    __shared__ float hred[2][C_];
    if ((tid & 63) == 0) {
        #pragma unroll
        for (int c = 0; c < C_; c++) hred[tid >> 6][c] = part[c];
    }
    __syncthreads();
    if (tid < C_)
        out[(size_t)row*C_ + tid] = hred[0][tid] + hred[1][tid] + hb[tid];
}

// ---------------------------------------------------------------------------
__global__ __launch_bounds__(256)
void cast_bf16_kernel(const float* __restrict__ in, unsigned short* __restrict__ out, int n)
{
    const int i = (blockIdx.x*256 + threadIdx.x)*4;
    if (i < n) {
        const float4 v = *(const float4*)(in + i);
        ushort4 o;
        o.x = f2bf(v.x); o.y = f2bf(v.y); o.z = f2bf(v.z); o.w = f2bf(v.w);
        *(ushort4*)(out + i) = o;
    }
}

// cast Wq/Wk/Wv into packed [L][1536][512] bf16
__global__ __launch_bounds__(256)
void cast_qkv_kernel(const float* __restrict__ Wq, const float* __restrict__ Wk,
                     const float* __restrict__ Wv, unsigned short* __restrict__ dst)
{
    const int t  = blockIdx.y;          // 0..17
    const int ll = t / 3, wh = t % 3;
    const int DD = D_*D_;
    const float* srcs[3] = {Wq, Wk, Wv};
    const float* src = srcs[wh] + (size_t)ll*DD;
    unsigned short* d = dst + (size_t)ll*3*DD + (size_t)wh*DD;
    const int i = (blockIdx.x*256 + threadIdx.x)*4;
    if (i < DD) {
        const float4 v = *(const float4*)(src + i);
        ushort4 o;
        o.x = f2bf(v.x); o.y = f2bf(v.y); o.z = f2bf(v.z); o.w = f2bf(v.w);
        *(ushort4*)(d + i) = o;
    }
}

// concat per-layer qkv bias: [L][1536] f32
__global__ __launch_bounds__(256)
void qkv_bias_kernel(const float* __restrict__ bq, const float* __restrict__ bk,
                     const float* __restrict__ bv, float* __restrict__ dst)
{
    const int idx = blockIdx.x*256 + threadIdx.x;   // < 6*1536
    const int ll = idx / 1536, c = idx % 1536;
    float v;
    if (c < 512)       v = bq[ll*512 + c];
    else if (c < 1024) v = bk[ll*512 + c - 512];
    else               v = bv[ll*512 + c - 1024];
    dst[idx] = v;
}

// ---------------------------------------------------------------------------
extern "C" void kernel_launch(void* const* d_in, const int* in_sizes, int n_in,
                              void* d_out, int out_size, void* d_ws, size_t ws_size,
                              hipStream_t stream)
{
    const float* src     = (const float*)d_in[0];
    const unsigned char* kpm = (const unsigned char*)d_in[1];
    const float* embed_W = (const float*)d_in[2];
    const float* embed_b = (const float*)d_in[3];
    const float* Wq = (const float*)d_in[4];
    const float* bq = (const float*)d_in[5];
    const float* Wk = (const float*)d_in[6];
    const float* bk = (const float*)d_in[7];
    const float* Wv = (const float*)d_in[8];
    const float* bv = (const float*)d_in[9];
    const float* Wo = (const float*)d_in[10];
    const float* bo = (const float*)d_in[11];
    const float* W1 = (const float*)d_in[12];
    const float* b1 = (const float*)d_in[13];
    const float* W2 = (const float*)d_in[14];
    const float* b2 = (const float*)d_in[15];
    const float* ln1_g = (const float*)d_in[16];
    const float* ln1_b = (const float*)d_in[17];
    const float* ln2_g = (const float*)d_in[18];
    const float* ln2_b = (const float*)d_in[19];
    const float* fin_g = (const float*)d_in[20];
    const float* fin_b = (const float*)d_in[21];
    const float* head_W = (const float*)d_in[22];
    const float* head_b = (const float*)d_in[23];
    float* out = (float*)d_out;

    float* ws = (float*)d_ws;
    const size_t S = (size_t)T_ * D_;             // 4,194,304
    float* x = ws;                                 // [0,S) f32
    unsigned short* u16  = (unsigned short*)(ws + S);
    unsigned short* xb   = u16;                    // S elems
    unsigned short* qkvb = u16 + 1*S;              // 3S elems: [T][1536]
    unsigned short* attb = u16 + 4*S;              // S elems
    unsigned short* tmpb = u16 + 5*S;              // S elems (bf16 deltas)
    unsigned short* h1b  = u16 + 1*S;              // 4S elems, aliases qkvb+attb (dead)
    unsigned short* wb   = u16 + 6*S;
    const int DD = D_*D_;
    const int DF = D_*FF_;
    unsigned short* wqkvb = wb;                    // 18*DD
    unsigned short* wob   = wb + 18*(size_t)DD;    // 6*DD
    unsigned short* w1b   = wb + 24*(size_t)DD;    // 24*DD
    unsigned short* w2b   = wb + 48*(size_t)DD;    // 24*DD
    float* qkvbias        = (float*)(wb + 72*(size_t)DD);  // 6*1536 f32
    unsigned short* srcb  = (unsigned short*)(qkvbias + 6*1536);   // T_*DIN
    unsigned short* embWb = srcb + (size_t)T_*DIN;                  // D_*DIN

    const dim3 blk(256);
    const dim3 gQKV(1536/128, T_/128);             // 12 x 64 = 768 blocks (%8==0)
    const dim3 gN512(D_/64,   T_/128);             // 8 x 64  = 512 blocks (%8==0)
    const dim3 gMF (FF_/128,  T_/128);             // 16 x 64 = 1024 blocks (%8==0)

    // one-time weight prep
    cast_qkv_kernel<<<dim3(DD/1024, 18), blk, 0, stream>>>(Wq, Wk, Wv, wqkvb);
    cast_bf16_kernel<<<6*DD/1024, blk, 0, stream>>>(Wo, wob, 6*DD);
    cast_bf16_kernel<<<6*DF/1024, blk, 0, stream>>>(W1, w1b, 6*DF);
    cast_bf16_kernel<<<6*DF/1024, blk, 0, stream>>>(W2, w2b, 6*DF);
    qkv_bias_kernel<<<(6*1536)/256, blk, 0, stream>>>(bq, bk, bv, qkvbias);
    cast_bf16_kernel<<<T_*DIN/1024, blk, 0, stream>>>(src, srcb, T_*DIN);
    cast_bf16_kernel<<<D_*DIN/1024, blk, 0, stream>>>(embed_W, embWb, D_*DIN);

    // embed via MFMA (K=64), dual f32 + bf16 output
    gemm_mfma_kernel<false,2,64><<<gN512, blk, 0, stream>>>(srcb, embWb, embed_b, x, xb, T_, D_, DIN);

    for (int l = 0; l < L_; l++) {
        const float* bol = bo + (size_t)l*D_;
        const float* b1l = b1 + (size_t)l*FF_;
        const float* b2l = b2 + (size_t)l*D_;

        // fused QKV projection -> qkvb [T][1536] bf16
        gemm_mfma_kernel<false,1,128><<<gQKV, blk, 0, stream>>>(xb, wqkvb + (size_t)l*3*DD,
                                                                qkvbias + (size_t)l*1536, qkvb, nullptr, T_, 1536, D_);

        attn_mfma_kernel<<<dim3(NSEQ/128, B_*H_), blk, 0, stream>>>(qkvb, kpm, attb);

        gemm_mfma_kernel<false,1,64><<<gN512, blk, 0, stream>>>(attb, wob + (size_t)l*DD, bol, tmpb, nullptr, T_, D_, D_);
        add_ln_kernel<<<T_, 128, 0, stream>>>(x, tmpb, ln1_g + (size_t)l*D_, ln1_b + (size_t)l*D_, xb);

        gemm_mfma_kernel<true, 1,128><<<gMF, blk, 0, stream>>>(xb, w1b + (size_t)l*DF, b1l, h1b, nullptr, T_, FF_, D_);
        gemm_mfma_kernel<false,1,64><<<gN512, blk, 0, stream>>>(h1b, w2b + (size_t)l*DF, b2l, tmpb, nullptr, T_, D_, FF_);
        add_ln_kernel<<<T_, 128, 0, stream>>>(x, tmpb, ln2_g + (size_t)l*D_, ln2_b + (size_t)l*D_, xb);
    }

    ln_head_kernel<<<T_, 128, 0, stream>>>(x, fin_g, fin_b, head_W, head_b, out);
}

// Round 10
// 1050.855 us; speedup vs baseline: 1.0572x; 1.0572x over previous
//
#include <hip/hip_runtime.h>
#include <hip/hip_bf16.h>
#include <math.h>

#define B_   8
#define NSEQ 1024
#define T_   (B_*NSEQ)     // 8192 tokens
#define DIN  64
#define D_   512
#define H_   8
#define HD_  64
#define FF_  2048
#define L_   6
#define C_   5

typedef __attribute__((ext_vector_type(8))) short bf16x8;
typedef __attribute__((ext_vector_type(4))) float f32x4;

__device__ __forceinline__ unsigned short f2bf(float f) {
    __hip_bfloat16 h = __float2bfloat16(f);
    return *reinterpret_cast<unsigned short*>(&h);
}
__device__ __forceinline__ float bf2f(unsigned short u) {
    __hip_bfloat16 h = *reinterpret_cast<__hip_bfloat16*>(&u);
    return __bfloat162float(h);
}

__device__ __forceinline__ void gload_lds16(const void* g, void* l) {
    __builtin_amdgcn_global_load_lds(
        (const __attribute__((address_space(1))) unsigned int*)g,
        (__attribute__((address_space(3))) unsigned int*)l, 16, 0, 0);
}

// ---------------------------------------------------------------------------
// bf16 MFMA GEMM, 2-phase double-buffered + bijective XCD swizzle (T1).
// BM=128, BK=64, BN template (128 or 64). 4 waves (2x2), 16x16x32 MFMA,
// XOR-swizzled LDS, global_load_lds staging overlapped with compute.
// Grid must have (gx*gy) % 8 == 0 (all our grids: 768/512/1024).
// ---------------------------------------------------------------------------
template<bool RELU, int BN>
__global__ __launch_bounds__(256, BN==64 ? 3 : 2)
void gemm_mfma_kernel(const unsigned short* __restrict__ A,
                      const unsigned short* __restrict__ W,
                      const float* __restrict__ bias,
                      unsigned short* __restrict__ Cout,
                      int M, int N, int K)
{
    constexpr int BM = 128, BK = 64;
    constexpr int NFN = BN/32;            // 4 (BN=128) or 2 (BN=64)
    __shared__ short As[2][BM*BK];
    __shared__ short Bs[2][BN*BK];
    const int tid = threadIdx.x;
    const int l   = tid & 63;
    const int wid = tid >> 6;
    const int wm  = wid >> 1, wn = wid & 1;

    // XCD swizzle: contiguous chunk of tiles per XCD for A-panel L2 reuse.
    const int gx  = gridDim.x;
    const int nwg = gx * gridDim.y;
    int bid = blockIdx.y * gx + blockIdx.x;
    bid = (bid & 7) * (nwg >> 3) + (bid >> 3);
    const int bm = (bid / gx) * BM;
    const int bn = (bid % gx) * BN;

    const int srow = l >> 3;
    const int scol = ((l & 7) ^ srow) * 8;

    f32x4 acc[4][NFN];
    const f32x4 z = {0.f, 0.f, 0.f, 0.f};
    #pragma unroll
    for (int m = 0; m < 4; m++)
        #pragma unroll
        for (int n = 0; n < NFN; n++) acc[m][n] = z;

    const int nk = K / BK;

    auto stage = [&](int kt, int sb) {
        const int k0 = kt * BK;
        #pragma unroll
        for (int c = 0; c < 4; c++) {
            const int r = wid*32 + c*8 + srow;
            gload_lds16(A + (size_t)(bm + r)*K + k0 + scol, &As[sb][(wid*32 + c*8)*64]);
        }
        #pragma unroll
        for (int c = 0; c < BN/32; c++) {
            const int r = wid*(BN/4) + c*8 + srow;
            gload_lds16(W + (size_t)(bn + r)*K + k0 + scol, &Bs[sb][(wid*(BN/4) + c*8)*64]);
        }
    };

    stage(0, 0);
    int buf = 0;
    for (int kt = 0; kt < nk; kt++) {
        __syncthreads();   // drains stage(kt): it had all of compute(kt-1) in flight
        if (kt + 1 < nk) stage(kt + 1, buf ^ 1);

        #pragma unroll
        for (int h = 0; h < 2; h++) {
            bf16x8 af[4], bfr[NFN];
            #pragma unroll
            for (int m = 0; m < 4; m++) {
                const int R  = wm*64 + m*16 + (l & 15);
                const int cb = (h*64 + (l >> 4)*16) ^ ((R & 7) << 4);
                af[m] = *(const bf16x8*)((const char*)&As[buf][0] + R*128 + cb);
            }
            #pragma unroll
            for (int n = 0; n < NFN; n++) {
                const int Rc = wn*(BN/2) + n*16 + (l & 15);
                const int cb = (h*64 + (l >> 4)*16) ^ ((Rc & 7) << 4);
                bfr[n] = *(const bf16x8*)((const char*)&Bs[buf][0] + Rc*128 + cb);
            }
            #pragma unroll
            for (int m = 0; m < 4; m++)
                #pragma unroll
                for (int n = 0; n < NFN; n++)
                    acc[m][n] = __builtin_amdgcn_mfma_f32_16x16x32_bf16(af[m], bfr[n], acc[m][n], 0, 0, 0);
        }
        buf ^= 1;
    }

    // C/D layout: col = lane&15, row = (lane>>4)*4 + reg   [m89-verified]
    #pragma unroll
    for (int n = 0; n < NFN; n++) {
        const int col = bn + wn*(BN/2) + n*16 + (l & 15);
        const float bv = bias[col];
        #pragma unroll
        for (int m = 0; m < 4; m++) {
            const int row0 = bm + wm*64 + m*16 + ((l >> 4) << 2);
            #pragma unroll
            for (int j = 0; j < 4; j++) {
                float t = acc[m][n][j] + bv;
                if (RELU) t = fmaxf(t, 0.f);
                Cout[(size_t)(row0 + j)*N + col] = f2bf(t);
            }
        }
    }
}

// ---------------------------------------------------------------------------
// bf16 MFMA flash attention v5 (unchanged from round 9 — passing, 57.4 us).
// ---------------------------------------------------------------------------
__global__ __launch_bounds__(256, 2)
void attn_mfma_kernel(const unsigned short* __restrict__ QKV,
                      const unsigned char* __restrict__ mask,
                      unsigned short* __restrict__ O)
{
    constexpr int QS = 1536;
    constexpr float CEXP = 0.18033688f;   // 0.125 * log2(e)
    __shared__ short Ks[2][64*64];
    __shared__ short Vt[2][64*72];
    __shared__ short Ps[4][32*72];
    const int tid = threadIdx.x;
    const int l   = tid & 63;
    const int w   = tid >> 6;
    const int g   = l >> 4;
    const int q16 = l & 15;
    const int b   = blockIdx.y >> 3;
    const int h   = blockIdx.y & 7;
    const int q0  = blockIdx.x * 128;
    const int qb  = q0 + w*32;
    const size_t tokbase = (size_t)b * NSEQ;

    bf16x8 bq[2][2];
    #pragma unroll
    for (int qf = 0; qf < 2; qf++) {
        const unsigned short* qp = QKV + (tokbase + qb + qf*16 + q16)*QS + h*HD_ + g*8;
        bq[qf][0] = *(const bf16x8*)qp;
        bq[qf][1] = *(const bf16x8*)(qp + 32);
    }

    f32x4 accO[2][4];
    const f32x4 z = {0.f,0.f,0.f,0.f};
    #pragma unroll
    for (int qf = 0; qf < 2; qf++)
        #pragma unroll
        for (int n = 0; n < 4; n++) accO[qf][n] = z;
    float mrow[2] = {-INFINITY, -INFINITY};   // RAW-score domain
    float lrow[2] = {0.f, 0.f};

    const int srow = l >> 3;
    const int scol = ((l & 7) ^ srow) * 8;
    const unsigned char* mp = mask + (size_t)b*NSEQ;

    #pragma unroll
    for (int c = 0; c < 2; c++) {
        const int rb = (w*2 + c)*8;
        gload_lds16(QKV + (tokbase + rb + srow)*QS + D_ + h*HD_ + scol, &Ks[0][rb*64]);
    }
    {
        const unsigned short* vp = QKV + (tokbase + l)*QS + 2*D_ + h*HD_ + w*16;
        const bf16x8 v8a = *(const bf16x8*)vp;
        const bf16x8 v8b = *(const bf16x8*)(vp + 8);
        #pragma unroll
        for (int j = 0; j < 8; j++) {
            Vt[0][(w*16 + j)*72 + l]     = v8a[j];
            Vt[0][(w*16 + 8 + j)*72 + l] = v8b[j];
        }
    }

    for (int t = 0; t < NSEQ/64; t++) {
        const int buf = t & 1;
        const int kv0 = t*64;
        __syncthreads();

        bf16x8 nva, nvb;
        const bool more = (t + 1 < NSEQ/64);
        if (more) {
            const int kvn = kv0 + 64;
            #pragma unroll
            for (int c = 0; c < 2; c++) {
                const int rb = (w*2 + c)*8;
                gload_lds16(QKV + (tokbase + kvn + rb + srow)*QS + D_ + h*HD_ + scol,
                            &Ks[buf^1][rb*64]);
            }
            const unsigned short* vp = QKV + (tokbase + kvn + l)*QS + 2*D_ + h*HD_ + w*16;
            nva = *(const bf16x8*)vp;
            nvb = *(const bf16x8*)(vp + 8);
        }

        f32x4 s4[2][4];
        #pragma unroll
        for (int qf = 0; qf < 2; qf++)
            #pragma unroll
            for (int n = 0; n < 4; n++) s4[qf][n] = z;
        __builtin_amdgcn_s_setprio(1);
        #pragma unroll
        for (int ks = 0; ks < 2; ks++) {
            const int cb = (ks*64 + g*16) ^ ((q16 & 7) << 4);
            bf16x8 ak[4];
            #pragma unroll
            for (int n = 0; n < 4; n++)
                ak[n] = *(const bf16x8*)((const char*)&Ks[buf][0] + (n*16 + q16)*128 + cb);
            #pragma unroll
            for (int qf = 0; qf < 2; qf++)
                #pragma unroll
                for (int n = 0; n < 4; n++)
                    s4[qf][n] = __builtin_amdgcn_mfma_f32_16x16x32_bf16(ak[n], bq[qf][ks], s4[qf][n], 0, 0, 0);
        }
        __builtin_amdgcn_s_setprio(0);

        const unsigned long long mbits = __ballot(mp[kv0 + l] != 0);

        #pragma unroll
        for (int qf = 0; qf < 2; qf++) {
            float sv[4][4];
            #pragma unroll
            for (int n = 0; n < 4; n++)
                #pragma unroll
                for (int r = 0; r < 4; r++) sv[n][r] = s4[qf][n][r];
            if (mbits) {
                #pragma unroll
                for (int n = 0; n < 4; n++)
                    #pragma unroll
                    for (int r = 0; r < 4; r++)
                        if ((mbits >> (unsigned)(16*n + 4*g + r)) & 1ULL) sv[n][r] = -INFINITY;
            }
            float tmax = sv[0][0];
            #pragma unroll
            for (int n = 0; n < 4; n++)
                #pragma unroll
                for (int r = 0; r < 4; r++) tmax = fmaxf(tmax, sv[n][r]);
            tmax = fmaxf(tmax, __shfl_xor(tmax, 16));
            tmax = fmaxf(tmax, __shfl_xor(tmax, 32));

            unsigned int pw[4][2];
            float rs = 0.f;
            if (__all(tmax <= mrow[qf] + 64.f)) {
                const float mc = mrow[qf]*CEXP;
                #pragma unroll
                for (int n = 0; n < 4; n++) {
                    const float p0 = exp2f(fmaf(sv[n][0], CEXP, -mc));
                    const float p1 = exp2f(fmaf(sv[n][1], CEXP, -mc));
                    const float p2 = exp2f(fmaf(sv[n][2], CEXP, -mc));
                    const float p3 = exp2f(fmaf(sv[n][3], CEXP, -mc));
                    pw[n][0] = (unsigned)f2bf(p0) | ((unsigned)f2bf(p1) << 16);
                    pw[n][1] = (unsigned)f2bf(p2) | ((unsigned)f2bf(p3) << 16);
                    rs += (p0 + p1) + (p2 + p3);
                }
                rs += __shfl_xor(rs, 16);
                rs += __shfl_xor(rs, 32);
                lrow[qf] += rs;
            } else {
                const float mnew = fmaxf(mrow[qf], tmax);
                const float mc   = mnew*CEXP;
                #pragma unroll
                for (int n = 0; n < 4; n++) {
                    const float p0 = exp2f(fmaf(sv[n][0], CEXP, -mc));
                    const float p1 = exp2f(fmaf(sv[n][1], CEXP, -mc));
                    const float p2 = exp2f(fmaf(sv[n][2], CEXP, -mc));
                    const float p3 = exp2f(fmaf(sv[n][3], CEXP, -mc));
                    pw[n][0] = (unsigned)f2bf(p0) | ((unsigned)f2bf(p1) << 16);
                    pw[n][1] = (unsigned)f2bf(p2) | ((unsigned)f2bf(p3) << 16);
                    rs += (p0 + p1) + (p2 + p3);
                }
                rs += __shfl_xor(rs, 16);
                rs += __shfl_xor(rs, 32);
                const float alpha = exp2f((mrow[qf] - mnew)*CEXP);
                lrow[qf] = lrow[qf]*alpha + rs;
                mrow[qf] = mnew;
                float alr[4];
                #pragma unroll
                for (int r = 0; r < 4; r++) alr[r] = __shfl(alpha, g*4 + r, 16);
                #pragma unroll
                for (int n = 0; n < 4; n++)
                    #pragma unroll
                    for (int r = 0; r < 4; r++) accO[qf][n][r] *= alr[r];
            }

            #pragma unroll
            for (int n = 0; n < 4; n++) {
                uint2 u; u.x = pw[n][0]; u.y = pw[n][1];
                *(uint2*)&Ps[w][(qf*16 + q16)*72 + 16*n + 4*g] = u;
            }
        }

        __builtin_amdgcn_s_setprio(1);
        #pragma unroll
        for (int ks = 0; ks < 2; ks++) {
            const bf16x8 ap0 = *(const bf16x8*)&Ps[w][(q16)*72      + ks*32 + g*8];
            const bf16x8 ap1 = *(const bf16x8*)&Ps[w][(16 + q16)*72 + ks*32 + g*8];
            #pragma unroll
            for (int n = 0; n < 4; n++) {
                const bf16x8 bv = *(const bf16x8*)&Vt[buf][(n*16 + q16)*72 + ks*32 + g*8];
                accO[0][n] = __builtin_amdgcn_mfma_f32_16x16x32_bf16(ap0, bv, accO[0][n], 0, 0, 0);
                accO[1][n] = __builtin_amdgcn_mfma_f32_16x16x32_bf16(ap1, bv, accO[1][n], 0, 0, 0);
            }
        }
        __builtin_amdgcn_s_setprio(0);

        if (more) {
            #pragma unroll
            for (int j = 0; j < 8; j++) {
                Vt[buf^1][(w*16 + j)*72 + l]     = nva[j];
                Vt[buf^1][(w*16 + 8 + j)*72 + l] = nvb[j];
            }
        }
    }

    #pragma unroll
    for (int qf = 0; qf < 2; qf++) {
        float linv[4];
        #pragma unroll
        for (int r = 0; r < 4; r++) linv[r] = 1.0f / __shfl(lrow[qf], g*4 + r, 16);
        #pragma unroll
        for (int r = 0; r < 4; r++) {
            unsigned short* op = O + (tokbase + qb + qf*16 + 4*g + r)*D_ + h*HD_;
            #pragma unroll
            for (int n = 0; n < 4; n++)
                op[16*n + q16] = f2bf(accO[qf][n][r] * linv[r]);
        }
    }
}

// ---------------------------------------------------------------------------
// Wave-per-row fused residual + LayerNorm, bf16 in-place:
// x[row] = bf16(LN(x[row] + delta[row]) * g + b). One 64-lane wave per row,
// 8 elems/lane in registers, shfl-only reduction (no LDS, no barrier).
// ---------------------------------------------------------------------------
__global__ __launch_bounds__(256)
void add_ln_kernel(unsigned short* __restrict__ x,
                   const unsigned short* __restrict__ delta,
                   const float* __restrict__ g, const float* __restrict__ bta)
{
    const int lane = threadIdx.x & 63;
    const int row  = blockIdx.x*4 + (threadIdx.x >> 6);
    unsigned short* xr = x + (size_t)row*D_ + lane*8;
    const bf16x8 xv8 = *(const bf16x8*)xr;
    const bf16x8 dv8 = *(const bf16x8*)(delta + (size_t)row*D_ + lane*8);
    float v[8], sum = 0.f, sq = 0.f;
    #pragma unroll
    for (int j = 0; j < 8; j++) {
        v[j] = bf2f((unsigned short)xv8[j]) + bf2f((unsigned short)dv8[j]);
        sum += v[j];
        sq  = fmaf(v[j], v[j], sq);
    }
    #pragma unroll
    for (int off = 1; off < 64; off <<= 1) {
        sum += __shfl_xor(sum, off, 64);
        sq  += __shfl_xor(sq,  off, 64);
    }
    const float mu  = sum * (1.f/D_);
    const float var = sq * (1.f/D_) - mu*mu;
    const float rs  = rsqrtf(var + 1e-5f);
    const float4 g0 = *(const float4*)(g + lane*8);
    const float4 g1 = *(const float4*)(g + lane*8 + 4);
    const float4 b0 = *(const float4*)(bta + lane*8);
    const float4 b1 = *(const float4*)(bta + lane*8 + 4);
    const float gf[8] = {g0.x,g0.y,g0.z,g0.w,g1.x,g1.y,g1.z,g1.w};
    const float bf_[8] = {b0.x,b0.y,b0.z,b0.w,b1.x,b1.y,b1.z,b1.w};
    bf16x8 o;
    #pragma unroll
    for (int j = 0; j < 8; j++)
        o[j] = (short)f2bf(fmaf((v[j] - mu)*rs, gf[j], bf_[j]));
    *(bf16x8*)xr = o;
}

// ---------------------------------------------------------------------------
// Wave-per-row fused final LayerNorm + head (C=5), bf16 x in, f32 logits out.
// ---------------------------------------------------------------------------
__global__ __launch_bounds__(256)
void ln_head_kernel(const unsigned short* __restrict__ x,
                    const float* __restrict__ g, const float* __restrict__ bta,
                    const float* __restrict__ hw, const float* __restrict__ hb,
                    float* __restrict__ out)
{
    const int lane = threadIdx.x & 63;
    const int row  = blockIdx.x*4 + (threadIdx.x >> 6);
    const bf16x8 xv8 = *(const bf16x8*)(x + (size_t)row*D_ + lane*8);
    float v[8], sum = 0.f, sq = 0.f;
    #pragma unroll
    for (int j = 0; j < 8; j++) {
        v[j] = bf2f((unsigned short)xv8[j]);
        sum += v[j];
        sq  = fmaf(v[j], v[j], sq);
    }
    #pragma unroll
    for (int off = 1; off < 64; off <<= 1) {
        sum += __shfl_xor(sum, off, 64);
        sq  += __shfl_xor(sq,  off, 64);
    }
    const float mu  = sum * (1.f/D_);
    const float var = sq * (1.f/D_) - mu*mu;
    const float rs  = rsqrtf(var + 1e-5f);
    const float4 g0 = *(const float4*)(g + lane*8);
    const float4 g1 = *(const float4*)(g + lane*8 + 4);
    const float4 b0 = *(const float4*)(bta + lane*8);
    const float4 b1 = *(const float4*)(bta + lane*8 + 4);
    const float gf[8] = {g0.x,g0.y,g0.z,g0.w,g1.x,g1.y,g1.z,g1.w};
    const float bf_[8] = {b0.x,b0.y,b0.z,b0.w,b1.x,b1.y,b1.z,b1.w};
    float o[8];
    #pragma unroll
    for (int j = 0; j < 8; j++)
        o[j] = fmaf((v[j] - mu)*rs, gf[j], bf_[j]);

    float part[C_];
    #pragma unroll
    for (int c = 0; c < C_; c++) {
        const float4 w0 = *(const float4*)(hw + c*D_ + lane*8);
        const float4 w1 = *(const float4*)(hw + c*D_ + lane*8 + 4);
        part[c] = o[0]*w0.x + o[1]*w0.y + o[2]*w0.z + o[3]*w0.w
                + o[4]*w1.x + o[5]*w1.y + o[6]*w1.z + o[7]*w1.w;
    }
    #pragma unroll
    for (int c = 0; c < C_; c++)
        #pragma unroll
        for (int off = 1; off < 64; off <<= 1)
            part[c] += __shfl_xor(part[c], off, 64);
    if (lane == 0) {
        #pragma unroll
        for (int c = 0; c < C_; c++)
            out[(size_t)row*C_ + c] = part[c] + hb[c];
    }
}

// ---------------------------------------------------------------------------
__global__ __launch_bounds__(256)
void cast_bf16_kernel(const float* __restrict__ in, unsigned short* __restrict__ out, int n)
{
    const int i = (blockIdx.x*256 + threadIdx.x)*4;
    if (i < n) {
        const float4 v = *(const float4*)(in + i);
        ushort4 o;
        o.x = f2bf(v.x); o.y = f2bf(v.y); o.z = f2bf(v.z); o.w = f2bf(v.w);
        *(ushort4*)(out + i) = o;
    }
}

// cast Wq/Wk/Wv into packed [L][1536][512] bf16
__global__ __launch_bounds__(256)
void cast_qkv_kernel(const float* __restrict__ Wq, const float* __restrict__ Wk,
                     const float* __restrict__ Wv, unsigned short* __restrict__ dst)
{
    const int t  = blockIdx.y;          // 0..17
    const int ll = t / 3, wh = t % 3;
    const int DD = D_*D_;
    const float* srcs[3] = {Wq, Wk, Wv};
    const float* src = srcs[wh] + (size_t)ll*DD;
    unsigned short* d = dst + (size_t)ll*3*DD + (size_t)wh*DD;
    const int i = (blockIdx.x*256 + threadIdx.x)*4;
    if (i < DD) {
        const float4 v = *(const float4*)(src + i);
        ushort4 o;
        o.x = f2bf(v.x); o.y = f2bf(v.y); o.z = f2bf(v.z); o.w = f2bf(v.w);
        *(ushort4*)(d + i) = o;
    }
}

// concat per-layer qkv bias: [L][1536] f32
__global__ __launch_bounds__(256)
void qkv_bias_kernel(const float* __restrict__ bq, const float* __restrict__ bk,
                     const float* __restrict__ bv, float* __restrict__ dst)
{
    const int idx = blockIdx.x*256 + threadIdx.x;   // < 6*1536
    const int ll = idx / 1536, c = idx % 1536;
    float v;
    if (c < 512)       v = bq[ll*512 + c];
    else if (c < 1024) v = bk[ll*512 + c - 512];
    else               v = bv[ll*512 + c - 1024];
    dst[idx] = v;
}

// ---------------------------------------------------------------------------
extern "C" void kernel_launch(void* const* d_in, const int* in_sizes, int n_in,
                              void* d_out, int out_size, void* d_ws, size_t ws_size,
                              hipStream_t stream)
{
    const float* src     = (const float*)d_in[0];
    const unsigned char* kpm = (const unsigned char*)d_in[1];
    const float* embed_W = (const float*)d_in[2];
    const float* embed_b = (const float*)d_in[3];
    const float* Wq = (const float*)d_in[4];
    const float* bq = (const float*)d_in[5];
    const float* Wk = (const float*)d_in[6];
    const float* bk = (const float*)d_in[7];
    const float* Wv = (const float*)d_in[8];
    const float* bv = (const float*)d_in[9];
    const float* Wo = (const float*)d_in[10];
    const float* bo = (const float*)d_in[11];
    const float* W1 = (const float*)d_in[12];
    const float* b1 = (const float*)d_in[13];
    const float* W2 = (const float*)d_in[14];
    const float* b2 = (const float*)d_in[15];
    const float* ln1_g = (const float*)d_in[16];
    const float* ln1_b = (const float*)d_in[17];
    const float* ln2_g = (const float*)d_in[18];
    const float* ln2_b = (const float*)d_in[19];
    const float* fin_g = (const float*)d_in[20];
    const float* fin_b = (const float*)d_in[21];
    const float* head_W = (const float*)d_in[22];
    const float* head_b = (const float*)d_in[23];
    float* out = (float*)d_out;

    const size_t S = (size_t)T_ * D_;             // 4,194,304
    unsigned short* u16  = (unsigned short*)d_ws;
    unsigned short* xb   = u16;                    // S elems (bf16 residual x)
    unsigned short* qkvb = u16 + 1*S;              // 3S elems: [T][1536]
    unsigned short* attb = u16 + 4*S;              // S elems
    unsigned short* tmpb = u16 + 5*S;              // S elems (bf16 deltas)
    unsigned short* h1b  = u16 + 1*S;              // 4S elems, aliases qkvb+attb (dead)
    unsigned short* wb   = u16 + 6*S;
    const int DD = D_*D_;
    const int DF = D_*FF_;
    unsigned short* wqkvb = wb;                    // 18*DD
    unsigned short* wob   = wb + 18*(size_t)DD;    // 6*DD
    unsigned short* w1b   = wb + 24*(size_t)DD;    // 24*DD
    unsigned short* w2b   = wb + 48*(size_t)DD;    // 24*DD
    float* qkvbias        = (float*)(wb + 72*(size_t)DD);  // 6*1536 f32
    unsigned short* srcb  = (unsigned short*)(qkvbias + 6*1536);   // T_*DIN
    unsigned short* embWb = srcb + (size_t)T_*DIN;                  // D_*DIN

    const dim3 blk(256);
    const dim3 gQKV(1536/128, T_/128);             // 12 x 64 = 768 blocks (%8==0)
    const dim3 gN512(D_/64,   T_/128);             // 8 x 64  = 512 blocks (%8==0)
    const dim3 gMF (FF_/128,  T_/128);             // 16 x 64 = 1024 blocks (%8==0)

    // one-time weight prep
    cast_qkv_kernel<<<dim3(DD/1024, 18), blk, 0, stream>>>(Wq, Wk, Wv, wqkvb);
    cast_bf16_kernel<<<6*DD/1024, blk, 0, stream>>>(Wo, wob, 6*DD);
    cast_bf16_kernel<<<6*DF/1024, blk, 0, stream>>>(W1, w1b, 6*DF);
    cast_bf16_kernel<<<6*DF/1024, blk, 0, stream>>>(W2, w2b, 6*DF);
    qkv_bias_kernel<<<(6*1536)/256, blk, 0, stream>>>(bq, bk, bv, qkvbias);
    cast_bf16_kernel<<<T_*DIN/1024, blk, 0, stream>>>(src, srcb, T_*DIN);
    cast_bf16_kernel<<<D_*DIN/1024, blk, 0, stream>>>(embed_W, embWb, D_*DIN);

    // embed via MFMA (K=64) -> xb (bf16 residual stream)
    gemm_mfma_kernel<false,64><<<gN512, blk, 0, stream>>>(srcb, embWb, embed_b, xb, T_, D_, DIN);

    for (int l = 0; l < L_; l++) {
        const float* bol = bo + (size_t)l*D_;
        const float* b1l = b1 + (size_t)l*FF_;
        const float* b2l = b2 + (size_t)l*D_;

        // fused QKV projection -> qkvb [T][1536] bf16
        gemm_mfma_kernel<false,128><<<gQKV, blk, 0, stream>>>(xb, wqkvb + (size_t)l*3*DD,
                                                              qkvbias + (size_t)l*1536, qkvb, T_, 1536, D_);

        attn_mfma_kernel<<<dim3(NSEQ/128, B_*H_), blk, 0, stream>>>(qkvb, kpm, attb);

        gemm_mfma_kernel<false,64><<<gN512, blk, 0, stream>>>(attb, wob + (size_t)l*DD, bol, tmpb, T_, D_, D_);
        add_ln_kernel<<<T_/4, blk, 0, stream>>>(xb, tmpb, ln1_g + (size_t)l*D_, ln1_b + (size_t)l*D_);

        gemm_mfma_kernel<true ,128><<<gMF, blk, 0, stream>>>(xb, w1b + (size_t)l*DF, b1l, h1b, T_, FF_, D_);
        gemm_mfma_kernel<false,64><<<gN512, blk, 0, stream>>>(h1b, w2b + (size_t)l*DF, b2l, tmpb, T_, D_, FF_);
        add_ln_kernel<<<T_/4, blk, 0, stream>>>(xb, tmpb, ln2_g + (size_t)l*D_, ln2_b + (size_t)l*D_);
    }

    ln_head_kernel<<<T_/4, blk, 0, stream>>>(xb, fin_g, fin_b, head_W, head_b, out);
}

// Round 11
// 988.380 us; speedup vs baseline: 1.1240x; 1.0632x over previous
//
#include <hip/hip_runtime.h>
#include <hip/hip_bf16.h>
#include <math.h>

#define B_   8
#define NSEQ 1024
#define T_   (B_*NSEQ)     // 8192 tokens
#define DIN  64
#define D_   512
#define H_   8
#define HD_  64
#define FF_  2048
#define L_   6
#define C_   5

typedef __attribute__((ext_vector_type(8))) short bf16x8;
typedef __attribute__((ext_vector_type(4))) float f32x4;

__device__ __forceinline__ unsigned short f2bf(float f) {
    __hip_bfloat16 h = __float2bfloat16(f);
    return *reinterpret_cast<unsigned short*>(&h);
}
__device__ __forceinline__ float bf2f(unsigned short u) {
    __hip_bfloat16 h = *reinterpret_cast<__hip_bfloat16*>(&u);
    return __bfloat162float(h);
}

__device__ __forceinline__ void gload_lds16(const void* g, void* l) {
    __builtin_amdgcn_global_load_lds(
        (const __attribute__((address_space(1))) unsigned int*)g,
        (__attribute__((address_space(3))) unsigned int*)l, 16, 0, 0);
}

// ---------------------------------------------------------------------------
// bf16 MFMA GEMM, single-buffer (m97 2-barrier structure) + XCD swizzle.
// BM=128, BK=64, BN template (128 or 64). 4 waves (2x2), 16x16x32 MFMA,
// XOR-swizzled LDS. launch_bounds(256,3): 3 blocks/CU where grid allows
// (32KB LDS, VGPR<=170) — cross-block overlap hides the barrier drain.
// Grid must have (gx*gy) % 8 == 0.
// ---------------------------------------------------------------------------
template<bool RELU, int BN>
__global__ __launch_bounds__(256, 3)
void gemm_mfma_kernel(const unsigned short* __restrict__ A,
                      const unsigned short* __restrict__ W,
                      const float* __restrict__ bias,
                      unsigned short* __restrict__ Cout,
                      int M, int N, int K)
{
    constexpr int BM = 128, BK = 64;
    constexpr int NFN = BN/32;            // 4 (BN=128) or 2 (BN=64)
    __shared__ short As[BM*BK];
    __shared__ short Bs[BN*BK];
    const int tid = threadIdx.x;
    const int l   = tid & 63;
    const int wid = tid >> 6;
    const int wm  = wid >> 1, wn = wid & 1;

    // XCD swizzle: contiguous chunk of tiles per XCD for A-panel L2 reuse.
    const int gx  = gridDim.x;
    const int nwg = gx * gridDim.y;
    int bid = blockIdx.y * gx + blockIdx.x;
    bid = (bid & 7) * (nwg >> 3) + (bid >> 3);
    const int bm = (bid / gx) * BM;
    const int bn = (bid % gx) * BN;

    const int srow = l >> 3;
    const int scol = ((l & 7) ^ srow) * 8;

    f32x4 acc[4][NFN];
    const f32x4 z = {0.f, 0.f, 0.f, 0.f};
    #pragma unroll
    for (int m = 0; m < 4; m++)
        #pragma unroll
        for (int n = 0; n < NFN; n++) acc[m][n] = z;

    const int nk = K / BK;
    for (int kt = 0; kt < nk; kt++) {
        const int k0 = kt * BK;
        __syncthreads();   // prev compute's LDS reads done
        #pragma unroll
        for (int c = 0; c < 4; c++) {
            const int r = wid*32 + c*8 + srow;
            gload_lds16(A + (size_t)(bm + r)*K + k0 + scol, &As[(wid*32 + c*8)*64]);
        }
        #pragma unroll
        for (int c = 0; c < BN/32; c++) {
            const int r = wid*(BN/4) + c*8 + srow;
            gload_lds16(W + (size_t)(bn + r)*K + k0 + scol, &Bs[(wid*(BN/4) + c*8)*64]);
        }
        __syncthreads();   // compiler drains vmcnt(0): tile ready

        #pragma unroll
        for (int h = 0; h < 2; h++) {
            bf16x8 af[4], bfr[NFN];
            #pragma unroll
            for (int m = 0; m < 4; m++) {
                const int R  = wm*64 + m*16 + (l & 15);
                const int cb = (h*64 + (l >> 4)*16) ^ ((R & 7) << 4);
                af[m] = *(const bf16x8*)((const char*)As + R*128 + cb);
            }
            #pragma unroll
            for (int n = 0; n < NFN; n++) {
                const int Rc = wn*(BN/2) + n*16 + (l & 15);
                const int cb = (h*64 + (l >> 4)*16) ^ ((Rc & 7) << 4);
                bfr[n] = *(const bf16x8*)((const char*)Bs + Rc*128 + cb);
            }
            #pragma unroll
            for (int m = 0; m < 4; m++)
                #pragma unroll
                for (int n = 0; n < NFN; n++)
                    acc[m][n] = __builtin_amdgcn_mfma_f32_16x16x32_bf16(af[m], bfr[n], acc[m][n], 0, 0, 0);
        }
    }

    // C/D layout: col = lane&15, row = (lane>>4)*4 + reg   [m89-verified]
    #pragma unroll
    for (int n = 0; n < NFN; n++) {
        const int col = bn + wn*(BN/2) + n*16 + (l & 15);
        const float bv = bias[col];
        #pragma unroll
        for (int m = 0; m < 4; m++) {
            const int row0 = bm + wm*64 + m*16 + ((l >> 4) << 2);
            #pragma unroll
            for (int j = 0; j < 4; j++) {
                float t = acc[m][n][j] + bv;
                if (RELU) t = fmaxf(t, 0.f);
                Cout[(size_t)(row0 + j)*N + col] = f2bf(t);
            }
        }
    }
}

// ---------------------------------------------------------------------------
// bf16 MFMA flash attention v6: v5 + XCD-coherent block remap so the 8
// q-blocks sharing one (b,h)'s K/V land on the same XCD (round-robin j%8).
// j = (bh>>3)*64 + q*8 + (bh&7)  (bijective on 512 blocks).
// ---------------------------------------------------------------------------
__global__ __launch_bounds__(256, 2)
void attn_mfma_kernel(const unsigned short* __restrict__ QKV,
                      const unsigned char* __restrict__ mask,
                      unsigned short* __restrict__ O)
{
    constexpr int QS = 1536;
    constexpr float CEXP = 0.18033688f;   // 0.125 * log2(e)
    __shared__ short Ks[2][64*64];
    __shared__ short Vt[2][64*72];
    __shared__ short Ps[4][32*72];
    const int tid = threadIdx.x;
    const int l   = tid & 63;
    const int w   = tid >> 6;
    const int g   = l >> 4;
    const int q16 = l & 15;

    // inverse of j = (bh>>3)*64 + q*8 + (bh&7): launch-id j -> (q, bh)
    const int j   = blockIdx.y * gridDim.x + blockIdx.x;
    const int qi  = (j >> 3) & 7;
    const int bh  = ((j >> 6) << 3) | (j & 7);
    const int b   = bh >> 3;
    const int h   = bh & 7;
    const int q0  = qi * 128;
    const int qb  = q0 + w*32;
    const size_t tokbase = (size_t)b * NSEQ;

    bf16x8 bq[2][2];
    #pragma unroll
    for (int qf = 0; qf < 2; qf++) {
        const unsigned short* qp = QKV + (tokbase + qb + qf*16 + q16)*QS + h*HD_ + g*8;
        bq[qf][0] = *(const bf16x8*)qp;
        bq[qf][1] = *(const bf16x8*)(qp + 32);
    }

    f32x4 accO[2][4];
    const f32x4 z = {0.f,0.f,0.f,0.f};
    #pragma unroll
    for (int qf = 0; qf < 2; qf++)
        #pragma unroll
        for (int n = 0; n < 4; n++) accO[qf][n] = z;
    float mrow[2] = {-INFINITY, -INFINITY};   // RAW-score domain
    float lrow[2] = {0.f, 0.f};

    const int srow = l >> 3;
    const int scol = ((l & 7) ^ srow) * 8;
    const unsigned char* mp = mask + (size_t)b*NSEQ;

    #pragma unroll
    for (int c = 0; c < 2; c++) {
        const int rb = (w*2 + c)*8;
        gload_lds16(QKV + (tokbase + rb + srow)*QS + D_ + h*HD_ + scol, &Ks[0][rb*64]);
    }
    {
        const unsigned short* vp = QKV + (tokbase + l)*QS + 2*D_ + h*HD_ + w*16;
        const bf16x8 v8a = *(const bf16x8*)vp;
        const bf16x8 v8b = *(const bf16x8*)(vp + 8);
        #pragma unroll
        for (int jj = 0; jj < 8; jj++) {
            Vt[0][(w*16 + jj)*72 + l]     = v8a[jj];
            Vt[0][(w*16 + 8 + jj)*72 + l] = v8b[jj];
        }
    }

    for (int t = 0; t < NSEQ/64; t++) {
        const int buf = t & 1;
        const int kv0 = t*64;
        __syncthreads();

        bf16x8 nva, nvb;
        const bool more = (t + 1 < NSEQ/64);
        if (more) {
            const int kvn = kv0 + 64;
            #pragma unroll
            for (int c = 0; c < 2; c++) {
                const int rb = (w*2 + c)*8;
                gload_lds16(QKV + (tokbase + kvn + rb + srow)*QS + D_ + h*HD_ + scol,
                            &Ks[buf^1][rb*64]);
            }
            const unsigned short* vp = QKV + (tokbase + kvn + l)*QS + 2*D_ + h*HD_ + w*16;
            nva = *(const bf16x8*)vp;
            nvb = *(const bf16x8*)(vp + 8);
        }

        f32x4 s4[2][4];
        #pragma unroll
        for (int qf = 0; qf < 2; qf++)
            #pragma unroll
            for (int n = 0; n < 4; n++) s4[qf][n] = z;
        __builtin_amdgcn_s_setprio(1);
        #pragma unroll
        for (int ks = 0; ks < 2; ks++) {
            const int cb = (ks*64 + g*16) ^ ((q16 & 7) << 4);
            bf16x8 ak[4];
            #pragma unroll
            for (int n = 0; n < 4; n++)
                ak[n] = *(const bf16x8*)((const char*)&Ks[buf][0] + (n*16 + q16)*128 + cb);
            #pragma unroll
            for (int qf = 0; qf < 2; qf++)
                #pragma unroll
                for (int n = 0; n < 4; n++)
                    s4[qf][n] = __builtin_amdgcn_mfma_f32_16x16x32_bf16(ak[n], bq[qf][ks], s4[qf][n], 0, 0, 0);
        }
        __builtin_amdgcn_s_setprio(0);

        const unsigned long long mbits = __ballot(mp[kv0 + l] != 0);

        #pragma unroll
        for (int qf = 0; qf < 2; qf++) {
            float sv[4][4];
            #pragma unroll
            for (int n = 0; n < 4; n++)
                #pragma unroll
                for (int r = 0; r < 4; r++) sv[n][r] = s4[qf][n][r];
            if (mbits) {
                #pragma unroll
                for (int n = 0; n < 4; n++)
                    #pragma unroll
                    for (int r = 0; r < 4; r++)
                        if ((mbits >> (unsigned)(16*n + 4*g + r)) & 1ULL) sv[n][r] = -INFINITY;
            }
            float tmax = sv[0][0];
            #pragma unroll
            for (int n = 0; n < 4; n++)
                #pragma unroll
                for (int r = 0; r < 4; r++) tmax = fmaxf(tmax, sv[n][r]);
            tmax = fmaxf(tmax, __shfl_xor(tmax, 16));
            tmax = fmaxf(tmax, __shfl_xor(tmax, 32));

            unsigned int pw[4][2];
            float rs = 0.f;
            if (__all(tmax <= mrow[qf] + 64.f)) {
                const float mc = mrow[qf]*CEXP;
                #pragma unroll
                for (int n = 0; n < 4; n++) {
                    const float p0 = exp2f(fmaf(sv[n][0], CEXP, -mc));
                    const float p1 = exp2f(fmaf(sv[n][1], CEXP, -mc));
                    const float p2 = exp2f(fmaf(sv[n][2], CEXP, -mc));
                    const float p3 = exp2f(fmaf(sv[n][3], CEXP, -mc));
                    pw[n][0] = (unsigned)f2bf(p0) | ((unsigned)f2bf(p1) << 16);
                    pw[n][1] = (unsigned)f2bf(p2) | ((unsigned)f2bf(p3) << 16);
                    rs += (p0 + p1) + (p2 + p3);
                }
                rs += __shfl_xor(rs, 16);
                rs += __shfl_xor(rs, 32);
                lrow[qf] += rs;
            } else {
                const float mnew = fmaxf(mrow[qf], tmax);
                const float mc   = mnew*CEXP;
                #pragma unroll
                for (int n = 0; n < 4; n++) {
                    const float p0 = exp2f(fmaf(sv[n][0], CEXP, -mc));
                    const float p1 = exp2f(fmaf(sv[n][1], CEXP, -mc));
                    const float p2 = exp2f(fmaf(sv[n][2], CEXP, -mc));
                    const float p3 = exp2f(fmaf(sv[n][3], CEXP, -mc));
                    pw[n][0] = (unsigned)f2bf(p0) | ((unsigned)f2bf(p1) << 16);
                    pw[n][1] = (unsigned)f2bf(p2) | ((unsigned)f2bf(p3) << 16);
                    rs += (p0 + p1) + (p2 + p3);
                }
                rs += __shfl_xor(rs, 16);
                rs += __shfl_xor(rs, 32);
                const float alpha = exp2f((mrow[qf] - mnew)*CEXP);
                lrow[qf] = lrow[qf]*alpha + rs;
                mrow[qf] = mnew;
                float alr[4];
                #pragma unroll
                for (int r = 0; r < 4; r++) alr[r] = __shfl(alpha, g*4 + r, 16);
                #pragma unroll
                for (int n = 0; n < 4; n++)
                    #pragma unroll
                    for (int r = 0; r < 4; r++) accO[qf][n][r] *= alr[r];
            }

            #pragma unroll
            for (int n = 0; n < 4; n++) {
                uint2 u; u.x = pw[n][0]; u.y = pw[n][1];
                *(uint2*)&Ps[w][(qf*16 + q16)*72 + 16*n + 4*g] = u;
            }
        }

        __builtin_amdgcn_s_setprio(1);
        #pragma unroll
        for (int ks = 0; ks < 2; ks++) {
            const bf16x8 ap0 = *(const bf16x8*)&Ps[w][(q16)*72      + ks*32 + g*8];
            const bf16x8 ap1 = *(const bf16x8*)&Ps[w][(16 + q16)*72 + ks*32 + g*8];
            #pragma unroll
            for (int n = 0; n < 4; n++) {
                const bf16x8 bv = *(const bf16x8*)&Vt[buf][(n*16 + q16)*72 + ks*32 + g*8];
                accO[0][n] = __builtin_amdgcn_mfma_f32_16x16x32_bf16(ap0, bv, accO[0][n], 0, 0, 0);
                accO[1][n] = __builtin_amdgcn_mfma_f32_16x16x32_bf16(ap1, bv, accO[1][n], 0, 0, 0);
            }
        }
        __builtin_amdgcn_s_setprio(0);

        if (more) {
            #pragma unroll
            for (int jj = 0; jj < 8; jj++) {
                Vt[buf^1][(w*16 + jj)*72 + l]     = nva[jj];
                Vt[buf^1][(w*16 + 8 + jj)*72 + l] = nvb[jj];
            }
        }
    }

    #pragma unroll
    for (int qf = 0; qf < 2; qf++) {
        float linv[4];
        #pragma unroll
        for (int r = 0; r < 4; r++) linv[r] = 1.0f / __shfl(lrow[qf], g*4 + r, 16);
        #pragma unroll
        for (int r = 0; r < 4; r++) {
            unsigned short* op = O + (tokbase + qb + qf*16 + 4*g + r)*D_ + h*HD_;
            #pragma unroll
            for (int n = 0; n < 4; n++)
                op[16*n + q16] = f2bf(accO[qf][n][r] * linv[r]);
        }
    }
}

// ---------------------------------------------------------------------------
// Wave-per-row fused residual + LayerNorm, bf16 in-place.
// ---------------------------------------------------------------------------
__global__ __launch_bounds__(256)
void add_ln_kernel(unsigned short* __restrict__ x,
                   const unsigned short* __restrict__ delta,
                   const float* __restrict__ g, const float* __restrict__ bta)
{
    const int lane = threadIdx.x & 63;
    const int row  = blockIdx.x*4 + (threadIdx.x >> 6);
    unsigned short* xr = x + (size_t)row*D_ + lane*8;
    const bf16x8 xv8 = *(const bf16x8*)xr;
    const bf16x8 dv8 = *(const bf16x8*)(delta + (size_t)row*D_ + lane*8);
    float v[8], sum = 0.f, sq = 0.f;
    #pragma unroll
    for (int j = 0; j < 8; j++) {
        v[j] = bf2f((unsigned short)xv8[j]) + bf2f((unsigned short)dv8[j]);
        sum += v[j];
        sq  = fmaf(v[j], v[j], sq);
    }
    #pragma unroll
    for (int off = 1; off < 64; off <<= 1) {
        sum += __shfl_xor(sum, off, 64);
        sq  += __shfl_xor(sq,  off, 64);
    }
    const float mu  = sum * (1.f/D_);
    const float var = sq * (1.f/D_) - mu*mu;
    const float rs  = rsqrtf(var + 1e-5f);
    const float4 g0 = *(const float4*)(g + lane*8);
    const float4 g1 = *(const float4*)(g + lane*8 + 4);
    const float4 b0 = *(const float4*)(bta + lane*8);
    const float4 b1 = *(const float4*)(bta + lane*8 + 4);
    const float gf[8] = {g0.x,g0.y,g0.z,g0.w,g1.x,g1.y,g1.z,g1.w};
    const float bf_[8] = {b0.x,b0.y,b0.z,b0.w,b1.x,b1.y,b1.z,b1.w};
    bf16x8 o;
    #pragma unroll
    for (int j = 0; j < 8; j++)
        o[j] = (short)f2bf(fmaf((v[j] - mu)*rs, gf[j], bf_[j]));
    *(bf16x8*)xr = o;
}

// ---------------------------------------------------------------------------
// Wave-per-row fused final LayerNorm + head (C=5).
// ---------------------------------------------------------------------------
__global__ __launch_bounds__(256)
void ln_head_kernel(const unsigned short* __restrict__ x,
                    const float* __restrict__ g, const float* __restrict__ bta,
                    const float* __restrict__ hw, const float* __restrict__ hb,
                    float* __restrict__ out)
{
    const int lane = threadIdx.x & 63;
    const int row  = blockIdx.x*4 + (threadIdx.x >> 6);
    const bf16x8 xv8 = *(const bf16x8*)(x + (size_t)row*D_ + lane*8);
    float v[8], sum = 0.f, sq = 0.f;
    #pragma unroll
    for (int j = 0; j < 8; j++) {
        v[j] = bf2f((unsigned short)xv8[j]);
        sum += v[j];
        sq  = fmaf(v[j], v[j], sq);
    }
    #pragma unroll
    for (int off = 1; off < 64; off <<= 1) {
        sum += __shfl_xor(sum, off, 64);
        sq  += __shfl_xor(sq,  off, 64);
    }
    const float mu  = sum * (1.f/D_);
    const float var = sq * (1.f/D_) - mu*mu;
    const float rs  = rsqrtf(var + 1e-5f);
    const float4 g0 = *(const float4*)(g + lane*8);
    const float4 g1 = *(const float4*)(g + lane*8 + 4);
    const float4 b0 = *(const float4*)(bta + lane*8);
    const float4 b1 = *(const float4*)(bta + lane*8 + 4);
    const float gf[8] = {g0.x,g0.y,g0.z,g0.w,g1.x,g1.y,g1.z,g1.w};
    const float bf_[8] = {b0.x,b0.y,b0.z,b0.w,b1.x,b1.y,b1.z,b1.w};
    float o[8];
    #pragma unroll
    for (int j = 0; j < 8; j++)
        o[j] = fmaf((v[j] - mu)*rs, gf[j], bf_[j]);

    float part[C_];
    #pragma unroll
    for (int c = 0; c < C_; c++) {
        const float4 w0 = *(const float4*)(hw + c*D_ + lane*8);
        const float4 w1 = *(const float4*)(hw + c*D_ + lane*8 + 4);
        part[c] = o[0]*w0.x + o[1]*w0.y + o[2]*w0.z + o[3]*w0.w
                + o[4]*w1.x + o[5]*w1.y + o[6]*w1.z + o[7]*w1.w;
    }
    #pragma unroll
    for (int c = 0; c < C_; c++)
        #pragma unroll
        for (int off = 1; off < 64; off <<= 1)
            part[c] += __shfl_xor(part[c], off, 64);
    if (lane == 0) {
        #pragma unroll
        for (int c = 0; c < C_; c++)
            out[(size_t)row*C_ + c] = part[c] + hb[c];
    }
}

// ---------------------------------------------------------------------------
__global__ __launch_bounds__(256)
void cast_bf16_kernel(const float* __restrict__ in, unsigned short* __restrict__ out, int n)
{
    const int i = (blockIdx.x*256 + threadIdx.x)*4;
    if (i < n) {
        const float4 v = *(const float4*)(in + i);
        ushort4 o;
        o.x = f2bf(v.x); o.y = f2bf(v.y); o.z = f2bf(v.z); o.w = f2bf(v.w);
        *(ushort4*)(out + i) = o;
    }
}

// cast Wq/Wk/Wv into packed [L][1536][512] bf16
__global__ __launch_bounds__(256)
void cast_qkv_kernel(const float* __restrict__ Wq, const float* __restrict__ Wk,
                     const float* __restrict__ Wv, unsigned short* __restrict__ dst)
{
    const int t  = blockIdx.y;          // 0..17
    const int ll = t / 3, wh = t % 3;
    const int DD = D_*D_;
    const float* srcs[3] = {Wq, Wk, Wv};
    const float* src = srcs[wh] + (size_t)ll*DD;
    unsigned short* d = dst + (size_t)ll*3*DD + (size_t)wh*DD;
    const int i = (blockIdx.x*256 + threadIdx.x)*4;
    if (i < DD) {
        const float4 v = *(const float4*)(src + i);
        ushort4 o;
        o.x = f2bf(v.x); o.y = f2bf(v.y); o.z = f2bf(v.z); o.w = f2bf(v.w);
        *(ushort4*)(d + i) = o;
    }
}

// concat per-layer qkv bias: [L][1536] f32
__global__ __launch_bounds__(256)
void qkv_bias_kernel(const float* __restrict__ bq, const float* __restrict__ bk,
                     const float* __restrict__ bv, float* __restrict__ dst)
{
    const int idx = blockIdx.x*256 + threadIdx.x;   // < 6*1536
    const int ll = idx / 1536, c = idx % 1536;
    float v;
    if (c < 512)       v = bq[ll*512 + c];
    else if (c < 1024) v = bk[ll*512 + c - 512];
    else               v = bv[ll*512 + c - 1024];
    dst[idx] = v;
}

// ---------------------------------------------------------------------------
extern "C" void kernel_launch(void* const* d_in, const int* in_sizes, int n_in,
                              void* d_out, int out_size, void* d_ws, size_t ws_size,
                              hipStream_t stream)
{
    const float* src     = (const float*)d_in[0];
    const unsigned char* kpm = (const unsigned char*)d_in[1];
    const float* embed_W = (const float*)d_in[2];
    const float* embed_b = (const float*)d_in[3];
    const float* Wq = (const float*)d_in[4];
    const float* bq = (const float*)d_in[5];
    const float* Wk = (const float*)d_in[6];
    const float* bk = (const float*)d_in[7];
    const float* Wv = (const float*)d_in[8];
    const float* bv = (const float*)d_in[9];
    const float* Wo = (const float*)d_in[10];
    const float* bo = (const float*)d_in[11];
    const float* W1 = (const float*)d_in[12];
    const float* b1 = (const float*)d_in[13];
    const float* W2 = (const float*)d_in[14];
    const float* b2 = (const float*)d_in[15];
    const float* ln1_g = (const float*)d_in[16];
    const float* ln1_b = (const float*)d_in[17];
    const float* ln2_g = (const float*)d_in[18];
    const float* ln2_b = (const float*)d_in[19];
    const float* fin_g = (const float*)d_in[20];
    const float* fin_b = (const float*)d_in[21];
    const float* head_W = (const float*)d_in[22];
    const float* head_b = (const float*)d_in[23];
    float* out = (float*)d_out;

    const size_t S = (size_t)T_ * D_;             // 4,194,304
    unsigned short* u16  = (unsigned short*)d_ws;
    unsigned short* xb   = u16;                    // S elems (bf16 residual x)
    unsigned short* qkvb = u16 + 1*S;              // 3S elems: [T][1536]
    unsigned short* attb = u16 + 4*S;              // S elems
    unsigned short* tmpb = u16 + 5*S;              // S elems (bf16 deltas)
    unsigned short* h1b  = u16 + 1*S;              // 4S elems, aliases qkvb+attb (dead)
    unsigned short* wb   = u16 + 6*S;
    const int DD = D_*D_;
    const int DF = D_*FF_;
    unsigned short* wqkvb = wb;                    // 18*DD
    unsigned short* wob   = wb + 18*(size_t)DD;    // 6*DD
    unsigned short* w1b   = wb + 24*(size_t)DD;    // 24*DD
    unsigned short* w2b   = wb + 48*(size_t)DD;    // 24*DD
    float* qkvbias        = (float*)(wb + 72*(size_t)DD);  // 6*1536 f32
    unsigned short* srcb  = (unsigned short*)(qkvbias + 6*1536);   // T_*DIN
    unsigned short* embWb = srcb + (size_t)T_*DIN;                  // D_*DIN

    const dim3 blk(256);
    const dim3 gQKV(1536/128, T_/128);             // 12 x 64 = 768 blocks (%8==0)
    const dim3 gN512(D_/64,   T_/128);             // 8 x 64  = 512 blocks (%8==0)
    const dim3 gMF (FF_/128,  T_/128);             // 16 x 64 = 1024 blocks (%8==0)

    // one-time weight prep
    cast_qkv_kernel<<<dim3(DD/1024, 18), blk, 0, stream>>>(Wq, Wk, Wv, wqkvb);
    cast_bf16_kernel<<<6*DD/1024, blk, 0, stream>>>(Wo, wob, 6*DD);
    cast_bf16_kernel<<<6*DF/1024, blk, 0, stream>>>(W1, w1b, 6*DF);
    cast_bf16_kernel<<<6*DF/1024, blk, 0, stream>>>(W2, w2b, 6*DF);
    qkv_bias_kernel<<<(6*1536)/256, blk, 0, stream>>>(bq, bk, bv, qkvbias);
    cast_bf16_kernel<<<T_*DIN/1024, blk, 0, stream>>>(src, srcb, T_*DIN);
    cast_bf16_kernel<<<D_*DIN/1024, blk, 0, stream>>>(embed_W, embWb, D_*DIN);

    // embed via MFMA (K=64) -> xb (bf16 residual stream)
    gemm_mfma_kernel<false,64><<<gN512, blk, 0, stream>>>(srcb, embWb, embed_b, xb, T_, D_, DIN);

    for (int l = 0; l < L_; l++) {
        const float* bol = bo + (size_t)l*D_;
        const float* b1l = b1 + (size_t)l*FF_;
        const float* b2l = b2 + (size_t)l*D_;

        // fused QKV projection -> qkvb [T][1536] bf16
        gemm_mfma_kernel<false,128><<<gQKV, blk, 0, stream>>>(xb, wqkvb + (size_t)l*3*DD,
                                                              qkvbias + (size_t)l*1536, qkvb, T_, 1536, D_);

        attn_mfma_kernel<<<dim3(NSEQ/128, B_*H_), blk, 0, stream>>>(qkvb, kpm, attb);

        gemm_mfma_kernel<false,64><<<gN512, blk, 0, stream>>>(attb, wob + (size_t)l*DD, bol, tmpb, T_, D_, D_);
        add_ln_kernel<<<T_/4, blk, 0, stream>>>(xb, tmpb, ln1_g + (size_t)l*D_, ln1_b + (size_t)l*D_);

        gemm_mfma_kernel<true ,128><<<gMF, blk, 0, stream>>>(xb, w1b + (size_t)l*DF, b1l, h1b, T_, FF_, D_);
        gemm_mfma_kernel<false,64><<<gN512, blk, 0, stream>>>(h1b, w2b + (size_t)l*DF, b2l, tmpb, T_, D_, FF_);
        add_ln_kernel<<<T_/4, blk, 0, stream>>>(xb, tmpb, ln2_g + (size_t)l*D_, ln2_b + (size_t)l*D_);
    }

    ln_head_kernel<<<T_/4, blk, 0, stream>>>(xb, fin_g, fin_b, head_W, head_b, out);
}